// Round 10
// baseline (442.258 us; speedup 1.0000x reference)
//
#include <hip/hip_runtime.h>

// GCN: 2x GraphConv(norm='both') + leaky_relu + linear classifier.
// Interface (validated R6/R7): x/W/b f32, src/dst int32, out f32.
// R10: bf16 feature staging (halves gather bytes + table footprint),
// unroll-8 gather with batched descriptor prefetch, isq folded into scan3.
// R8/R9 lessons: resident waves are capped ~12/CU regardless of grid; W held
// as explicit L1 loads (lean regs) == register-W in perf; don't fatten waves.

__device__ __forceinline__ float b2f(unsigned short u) {
    return __uint_as_float(((unsigned int)u) << 16);
}
__device__ __forceinline__ unsigned short f2b(float f) {
    unsigned int i = __float_as_uint(f);
    unsigned int r = (i + 0x7FFFu + ((i >> 16) & 1u)) >> 16;  // RNE
    return (unsigned short)r;
}

__global__ void deg_kernel(const int* __restrict__ src, const int* __restrict__ dst,
                           int* dout, int* din, int e) {
    int i = blockIdx.x * blockDim.x + threadIdx.x;
    if (i < e) {
        atomicAdd(&dout[src[i]], 1);
        atomicAdd(&din[dst[i]], 1);
    }
}

// ---- exclusive prefix scan of deg_in -> row offsets ----
__global__ void scan1_kernel(const int* __restrict__ deg, int* row, int* partials, int n) {
    __shared__ int s[1024];
    int t = threadIdx.x;
    int i = blockIdx.x * 1024 + t;
    int v = (i < n) ? deg[i] : 0;
    s[t] = v;
    __syncthreads();
    for (int d = 1; d < 1024; d <<= 1) {
        int x = (t >= d) ? s[t - d] : 0;
        __syncthreads();
        s[t] += x;
        __syncthreads();
    }
    if (i < n) row[i] = s[t] - v;  // exclusive within chunk
    if (t == 1023) partials[blockIdx.x] = s[1023];
}

// parallel scan of chunk totals (nchunks <= 1024), single block
__global__ void scan2_kernel(int* partials, int nchunks, int* row, int n) {
    __shared__ int s[1024];
    int t = threadIdx.x;
    int v = (t < nchunks) ? partials[t] : 0;
    s[t] = v;
    __syncthreads();
    for (int d = 1; d < 1024; d <<= 1) {
        int x = (t >= d) ? s[t - d] : 0;
        __syncthreads();
        s[t] += x;
        __syncthreads();
    }
    if (t < nchunks) partials[t] = s[t] - v;  // exclusive
    if (t == nchunks - 1) row[n] = s[t];      // total == E
}

// add chunk bases; init cursor; compute degree rsqrt (isq fused here)
__global__ void scan3_kernel(int* row, int* cursor, const int* __restrict__ partials,
                             const int* __restrict__ dout, const int* __restrict__ din,
                             float* oi, float* ii, int n) {
    int i = blockIdx.x * blockDim.x + threadIdx.x;
    if (i < n) {
        int r = row[i] + partials[i >> 10];
        row[i] = r;
        cursor[i] = r;
        oi[i] = rsqrtf((float)max(dout[i], 1));
        ii[i] = rsqrtf((float)max(din[i], 1));
    }
}

// csr2[p] = { src, oi[src] }  (cursor pre-initialized to row offsets)
__global__ void scatter_kernel(const int* __restrict__ src, const int* __restrict__ dst,
                               const float* __restrict__ oi, int* cursor, int2* csr2, int e) {
    int i = blockIdx.x * blockDim.x + threadIdx.x;
    if (i < e) {
        int s = src[i];
        int p = atomicAdd(&cursor[dst[i]], 1);
        csr2[p] = make_int2(s, __float_as_int(oi[s]));
    }
}

// xb = bf16(x), 4 elements/thread
__global__ void xconv_kernel(const float* __restrict__ x, ushort4* __restrict__ xb, int quads) {
    int i = blockIdx.x * blockDim.x + threadIdx.x;
    if (i < quads) {
        float4 v = ((const float4*)x)[i];
        xb[i] = make_ushort4(f2b(v.x), f2b(v.y), f2b(v.z), f2b(v.w));
    }
}

// One wave per node (grid-stride). Lane = feature. bf16 feature gathers with
// per-edge oi weight; unroll-8 with descriptor prefetch batch; matvec via
// readlane broadcast with W streamed from L1 (lean registers).
template <bool FINAL>
__global__ __launch_bounds__(256) void layer_kernel(
    const unsigned short* __restrict__ feat, const int* __restrict__ row,
    const int2* __restrict__ csr2, const float* __restrict__ ii,
    const float* __restrict__ W, const float* __restrict__ bias,
    const float* __restrict__ Wc, const float* __restrict__ bcl,
    void* __restrict__ out, int n, int nwaves) {
    int lane = threadIdx.x & 63;
    int wid = blockIdx.x * (blockDim.x >> 6) + (threadIdx.x >> 6);

    float bl = bias[lane];
    float wc0 = 0.f, wc1 = 0.f, bc0 = 0.f, bc1 = 0.f;
    if constexpr (FINAL) {
        wc0 = Wc[lane * 2];
        wc1 = Wc[lane * 2 + 1];
        bc0 = bcl[0];
        bc1 = bcl[1];
    }

    for (int v = wid; v < n; v += nwaves) {
        int s0 = row[v], s1 = row[v + 1];
        float acc = 0.f;
        int i = s0;
        for (; i + 7 < s1; i += 8) {  // 8 descriptors, then 8 gathers in flight
            int2 e0 = csr2[i],     e1 = csr2[i + 1], e2 = csr2[i + 2], e3 = csr2[i + 3];
            int2 e4 = csr2[i + 4], e5 = csr2[i + 5], e6 = csr2[i + 6], e7 = csr2[i + 7];
            float f0 = b2f(feat[(size_t)e0.x * 64 + lane]);
            float f1 = b2f(feat[(size_t)e1.x * 64 + lane]);
            float f2 = b2f(feat[(size_t)e2.x * 64 + lane]);
            float f3 = b2f(feat[(size_t)e3.x * 64 + lane]);
            float f4 = b2f(feat[(size_t)e4.x * 64 + lane]);
            float f5 = b2f(feat[(size_t)e5.x * 64 + lane]);
            float f6 = b2f(feat[(size_t)e6.x * 64 + lane]);
            float f7 = b2f(feat[(size_t)e7.x * 64 + lane]);
            acc = fmaf(f0, __int_as_float(e0.y), acc);
            acc = fmaf(f1, __int_as_float(e1.y), acc);
            acc = fmaf(f2, __int_as_float(e2.y), acc);
            acc = fmaf(f3, __int_as_float(e3.y), acc);
            acc = fmaf(f4, __int_as_float(e4.y), acc);
            acc = fmaf(f5, __int_as_float(e5.y), acc);
            acc = fmaf(f6, __int_as_float(e6.y), acc);
            acc = fmaf(f7, __int_as_float(e7.y), acc);
        }
        for (; i < s1; i++) {
            int2 ee = csr2[i];
            acc = fmaf(b2f(feat[(size_t)ee.x * 64 + lane]), __int_as_float(ee.y), acc);
        }

        float t = acc * ii[v];  // lane k holds aggregated row element k
        float o = bl;
#pragma unroll
        for (int k = 0; k < 64; k++) {
            float w = W[k * 64 + lane];  // L1-resident 16 KB
            float bk = __uint_as_float(
                (unsigned)__builtin_amdgcn_readlane((int)__float_as_uint(t), k));
            o = fmaf(bk, w, o);
        }
        o = (o > 0.f) ? o : 0.01f * o;  // leaky relu

        if constexpr (!FINAL) {
            ((unsigned short*)out)[(size_t)v * 64 + lane] = f2b(o);
        } else {
            float p0 = o * wc0, p1 = o * wc1;
#pragma unroll
            for (int off = 32; off; off >>= 1) {
                p0 += __shfl_down(p0, off);
                p1 += __shfl_down(p1, off);
            }
            if (lane == 0) ((float2*)out)[v] = make_float2(p0 + bc0, p1 + bc1);
        }
    }
}

extern "C" void kernel_launch(void* const* d_in, const int* in_sizes, int n_in,
                              void* d_out, int out_size, void* d_ws, size_t ws_size,
                              hipStream_t stream) {
    const float* x  = (const float*)d_in[0];
    const int* src  = (const int*)d_in[1];
    const int* dst  = (const int*)d_in[2];
    const float* W1 = (const float*)d_in[3];
    const float* b1 = (const float*)d_in[4];
    const float* W2 = (const float*)d_in[5];
    const float* b2 = (const float*)d_in[6];
    const float* Wc = (const float*)d_in[7];
    const float* bc = (const float*)d_in[8];
    int n = in_sizes[0] / 64;
    int e = in_sizes[1];
    int total = n * 64;

    char* ws = (char*)d_ws;
    size_t off = 0;
    auto take = [&](size_t bytes) -> char* {
        char* p = ws + off;
        off = (off + bytes + 255) & ~(size_t)255;
        return p;
    };
    int* deg_out  = (int*)take((size_t)n * 4);
    int* deg_in   = (int*)take((size_t)n * 4);
    int* cursor   = (int*)take((size_t)n * 4);
    int* row      = (int*)take((size_t)(n + 1) * 4);
    int* partials = (int*)take(4096);
    int2* csr2    = (int2*)take((size_t)e * 8);        // 8 MB
    float* oi     = (float*)take((size_t)n * 4);
    float* ii     = (float*)take((size_t)n * 4);
    unsigned short* xb  = (unsigned short*)take((size_t)total * 2);  // 12.8 MB
    unsigned short* h1b = (unsigned short*)take((size_t)total * 2);  // 12.8 MB

    const int tb = 256;
    // zero deg_out + deg_in (contiguous carve-outs)
    size_t zbytes = (size_t)((char*)deg_in + (size_t)n * 4 - (char*)deg_out);
    hipMemsetAsync(deg_out, 0, zbytes, stream);

    deg_kernel<<<(e + tb - 1) / tb, tb, 0, stream>>>(src, dst, deg_out, deg_in, e);

    int nchunks = (n + 1023) / 1024;
    scan1_kernel<<<nchunks, 1024, 0, stream>>>(deg_in, row, partials, n);
    scan2_kernel<<<1, 1024, 0, stream>>>(partials, nchunks, row, n);
    scan3_kernel<<<(n + tb - 1) / tb, tb, 0, stream>>>(row, cursor, partials,
                                                       deg_out, deg_in, oi, ii, n);
    scatter_kernel<<<(e + tb - 1) / tb, tb, 0, stream>>>(src, dst, oi, cursor, csr2, e);
    xconv_kernel<<<(total / 4 + tb - 1) / tb, tb, 0, stream>>>(x, (ushort4*)xb, total / 4);

    const int lblocks = 2048;
    const int nwaves = lblocks * (tb / 64);
    layer_kernel<false><<<lblocks, tb, 0, stream>>>(xb, row, csr2, ii, W1, b1,
                                                    nullptr, nullptr, h1b, n, nwaves);
    layer_kernel<true><<<lblocks, tb, 0, stream>>>(h1b, row, csr2, ii, W2, b2,
                                                   Wc, bc, d_out, n, nwaves);
}

// Round 11
// 333.933 us; speedup vs baseline: 1.3244x; 1.3244x over previous
//
#include <hip/hip_runtime.h>

// GCN: 2x GraphConv(norm='both') + leaky_relu + linear classifier.
// Interface (validated R6/R7): x/W/b f32, src/dst int32, out f32.
// R11: layer split into (a) VMEM-lean float4 gather-aggregate (wave = 4 nodes
// x 16 lanes x float4 => 1 gather inst per 4 edges) and (b) MFMA bf16 GEMM
// for the 64x64 transform (W frags in registers, ii/bias/leaky/classifier
// fused). R10 lesson: layer kernel was VMEM-instruction bound (64 W loads
// per node in the readlane matvec), not bandwidth bound.

typedef __attribute__((ext_vector_type(8))) short short8;
typedef __attribute__((ext_vector_type(4))) float f32x4;

__device__ __forceinline__ unsigned short f2b(float f) {
    unsigned int i = __float_as_uint(f);
    unsigned int r = (i + 0x7FFFu + ((i >> 16) & 1u)) >> 16;  // RNE
    return (unsigned short)r;
}

__global__ void deg_kernel(const int* __restrict__ src, const int* __restrict__ dst,
                           int* dout, int* din, int e) {
    int i = blockIdx.x * blockDim.x + threadIdx.x;
    if (i < e) {
        atomicAdd(&dout[src[i]], 1);
        atomicAdd(&din[dst[i]], 1);
    }
}

// ---- exclusive prefix scan of deg_in -> row offsets ----
__global__ void scan1_kernel(const int* __restrict__ deg, int* row, int* partials, int n) {
    __shared__ int s[1024];
    int t = threadIdx.x;
    int i = blockIdx.x * 1024 + t;
    int v = (i < n) ? deg[i] : 0;
    s[t] = v;
    __syncthreads();
    for (int d = 1; d < 1024; d <<= 1) {
        int x = (t >= d) ? s[t - d] : 0;
        __syncthreads();
        s[t] += x;
        __syncthreads();
    }
    if (i < n) row[i] = s[t] - v;  // exclusive within chunk
    if (t == 1023) partials[blockIdx.x] = s[1023];
}

__global__ void scan2_kernel(int* partials, int nchunks, int* row, int n) {
    __shared__ int s[1024];
    int t = threadIdx.x;
    int v = (t < nchunks) ? partials[t] : 0;
    s[t] = v;
    __syncthreads();
    for (int d = 1; d < 1024; d <<= 1) {
        int x = (t >= d) ? s[t - d] : 0;
        __syncthreads();
        s[t] += x;
        __syncthreads();
    }
    if (t < nchunks) partials[t] = s[t] - v;  // exclusive
    if (t == nchunks - 1) row[n] = s[t];      // total == E
}

// add chunk bases; init cursor; degree rsqrt
__global__ void scan3_kernel(int* row, int* cursor, const int* __restrict__ partials,
                             const int* __restrict__ dout, const int* __restrict__ din,
                             float* oi, float* ii, int n) {
    int i = blockIdx.x * blockDim.x + threadIdx.x;
    if (i < n) {
        int r = row[i] + partials[i >> 10];
        row[i] = r;
        cursor[i] = r;
        oi[i] = rsqrtf((float)max(dout[i], 1));
        ii[i] = rsqrtf((float)max(din[i], 1));
    }
}

// csr2[p] = { src, oi[src] }
__global__ void scatter_kernel(const int* __restrict__ src, const int* __restrict__ dst,
                               const float* __restrict__ oi, int* cursor, int2* csr2, int e) {
    int i = blockIdx.x * blockDim.x + threadIdx.x;
    if (i < e) {
        int s = src[i];
        int p = atomicAdd(&cursor[dst[i]], 1);
        csr2[p] = make_int2(s, __float_as_int(oi[s]));
    }
}

// Aggregate: wave handles 4 nodes; quad q = lane>>4 owns node vbase+q;
// sublane s = lane&15 owns features 4s..4s+3 (float4). One feat gather
// instruction serves 4 edges (one per quad). out[v] = sum oi[src]*feat[src].
__global__ __launch_bounds__(256) void agg_kernel(
    const float4* __restrict__ feat4, const int* __restrict__ row,
    const int2* __restrict__ csr2, float4* __restrict__ out4,
    int n, int nwaves) {
    int lane = threadIdx.x & 63;
    int q = lane >> 4, s = lane & 15;
    int wid = blockIdx.x * (blockDim.x >> 6) + (threadIdx.x >> 6);
    int ngroups = (n + 3) >> 2;

    for (int g = wid; g < ngroups; g += nwaves) {
        int v = (g << 2) + q;
        bool valid = v < n;
        int base = 0, cnt = 0;
        if (valid) { base = row[v]; cnt = row[v + 1] - base; }
        float4 a = make_float4(0.f, 0.f, 0.f, 0.f);
        int j = 0;
        for (; j + 3 < cnt; j += 4) {  // 4 edges x 4 quads of loads in flight
            int2 e0 = csr2[base + j],     e1 = csr2[base + j + 1];
            int2 e2 = csr2[base + j + 2], e3 = csr2[base + j + 3];
            float4 f0 = feat4[(size_t)e0.x * 16 + s];
            float4 f1 = feat4[(size_t)e1.x * 16 + s];
            float4 f2 = feat4[(size_t)e2.x * 16 + s];
            float4 f3 = feat4[(size_t)e3.x * 16 + s];
            float w0 = __int_as_float(e0.y), w1 = __int_as_float(e1.y);
            float w2 = __int_as_float(e2.y), w3 = __int_as_float(e3.y);
            a.x = fmaf(f0.x, w0, a.x); a.y = fmaf(f0.y, w0, a.y);
            a.z = fmaf(f0.z, w0, a.z); a.w = fmaf(f0.w, w0, a.w);
            a.x = fmaf(f1.x, w1, a.x); a.y = fmaf(f1.y, w1, a.y);
            a.z = fmaf(f1.z, w1, a.z); a.w = fmaf(f1.w, w1, a.w);
            a.x = fmaf(f2.x, w2, a.x); a.y = fmaf(f2.y, w2, a.y);
            a.z = fmaf(f2.z, w2, a.z); a.w = fmaf(f2.w, w2, a.w);
            a.x = fmaf(f3.x, w3, a.x); a.y = fmaf(f3.y, w3, a.y);
            a.z = fmaf(f3.z, w3, a.z); a.w = fmaf(f3.w, w3, a.w);
        }
        for (; j < cnt; j++) {
            int2 ee = csr2[base + j];
            float4 f = feat4[(size_t)ee.x * 16 + s];
            float w = __int_as_float(ee.y);
            a.x = fmaf(f.x, w, a.x); a.y = fmaf(f.y, w, a.y);
            a.z = fmaf(f.z, w, a.z); a.w = fmaf(f.w, w, a.w);
        }
        if (valid) out4[(size_t)v * 16 + s] = a;
    }
}

// Transform: [n x 64] @ W[64 x 64] via mfma_f32_16x16x32_bf16.
// Wave computes 16 rows x 64 cols per group. A: m=lane&15, k=quad*8+j;
// B: n=lane&15, k=quad*8+j; C/D: col=lane&15, row=quad*4+reg (verified).
// ii folded into A load; bias+leaky in epilogue; FINAL fuses 64->2 classifier.
template <bool FINAL>
__global__ __launch_bounds__(256) void gemm_kernel(
    const float* __restrict__ agg, const float* __restrict__ ii,
    const float* __restrict__ W, const float* __restrict__ bias,
    const float* __restrict__ Wc, const float* __restrict__ bcl,
    float* __restrict__ out, int n, int nwaves) {
    int lane = threadIdx.x & 63;
    int m15 = lane & 15, quad = lane >> 4;
    int wid = blockIdx.x * (blockDim.x >> 6) + (threadIdx.x >> 6);
    int ngroups = (n + 15) >> 4;

    // Hoisted B fragments: bf[nt][kk], element j holds W[kk*32+quad*8+j][nt*16+m15]
    short8 bf[4][2];
#pragma unroll
    for (int nt = 0; nt < 4; nt++)
#pragma unroll
        for (int kk = 0; kk < 2; kk++)
#pragma unroll
            for (int j = 0; j < 8; j++)
                bf[nt][kk][j] = (short)f2b(W[(kk * 32 + quad * 8 + j) * 64 + nt * 16 + m15]);

    float bias_r[4];
#pragma unroll
    for (int nt = 0; nt < 4; nt++) bias_r[nt] = bias[nt * 16 + m15];

    float wc_r[4][2];
    float bc0 = 0.f, bc1 = 0.f;
    if constexpr (FINAL) {
#pragma unroll
        for (int nt = 0; nt < 4; nt++) {
            wc_r[nt][0] = Wc[(nt * 16 + m15) * 2];
            wc_r[nt][1] = Wc[(nt * 16 + m15) * 2 + 1];
        }
        bc0 = bcl[0];
        bc1 = bcl[1];
    }

    for (int g = wid; g < ngroups; g += nwaves) {
        int rbase = g << 4;
        int rm = min(rbase + m15, n - 1);       // clamp for tail group
        float iiv = ii[rm];

        short8 af[2];
#pragma unroll
        for (int kk = 0; kk < 2; kk++) {
            const float4* p = (const float4*)(agg + (size_t)rm * 64 + kk * 32 + quad * 8);
            float4 x0 = p[0], x1 = p[1];
            af[kk][0] = (short)f2b(x0.x * iiv);
            af[kk][1] = (short)f2b(x0.y * iiv);
            af[kk][2] = (short)f2b(x0.z * iiv);
            af[kk][3] = (short)f2b(x0.w * iiv);
            af[kk][4] = (short)f2b(x1.x * iiv);
            af[kk][5] = (short)f2b(x1.y * iiv);
            af[kk][6] = (short)f2b(x1.z * iiv);
            af[kk][7] = (short)f2b(x1.w * iiv);
        }

        f32x4 acc[4];
#pragma unroll
        for (int nt = 0; nt < 4; nt++) {
            f32x4 z = {0.f, 0.f, 0.f, 0.f};
            z = __builtin_amdgcn_mfma_f32_16x16x32_bf16(af[0], bf[nt][0], z, 0, 0, 0);
            z = __builtin_amdgcn_mfma_f32_16x16x32_bf16(af[1], bf[nt][1], z, 0, 0, 0);
            acc[nt] = z;
        }

        if constexpr (!FINAL) {
#pragma unroll
            for (int nt = 0; nt < 4; nt++)
#pragma unroll
                for (int r = 0; r < 4; r++) {
                    int vr = rbase + quad * 4 + r;
                    float o = acc[nt][r] + bias_r[nt];
                    o = (o > 0.f) ? o : 0.01f * o;
                    if (vr < n) out[(size_t)vr * 64 + nt * 16 + m15] = o;
                }
        } else {
#pragma unroll
            for (int r = 0; r < 4; r++) {
                float p0 = 0.f, p1 = 0.f;
#pragma unroll
                for (int nt = 0; nt < 4; nt++) {
                    float o = acc[nt][r] + bias_r[nt];
                    o = (o > 0.f) ? o : 0.01f * o;
                    p0 = fmaf(o, wc_r[nt][0], p0);
                    p1 = fmaf(o, wc_r[nt][1], p1);
                }
#pragma unroll
                for (int off = 1; off < 16; off <<= 1) {
                    p0 += __shfl_xor(p0, off);
                    p1 += __shfl_xor(p1, off);
                }
                int vr = rbase + quad * 4 + r;
                if (m15 == 0 && vr < n)
                    ((float2*)out)[vr] = make_float2(p0 + bc0, p1 + bc1);
            }
        }
    }
}

extern "C" void kernel_launch(void* const* d_in, const int* in_sizes, int n_in,
                              void* d_out, int out_size, void* d_ws, size_t ws_size,
                              hipStream_t stream) {
    const float* x  = (const float*)d_in[0];
    const int* src  = (const int*)d_in[1];
    const int* dst  = (const int*)d_in[2];
    const float* W1 = (const float*)d_in[3];
    const float* b1 = (const float*)d_in[4];
    const float* W2 = (const float*)d_in[5];
    const float* b2 = (const float*)d_in[6];
    const float* Wc = (const float*)d_in[7];
    const float* bc = (const float*)d_in[8];
    int n = in_sizes[0] / 64;
    int e = in_sizes[1];
    int total = n * 64;

    char* ws = (char*)d_ws;
    size_t off = 0;
    auto take = [&](size_t bytes) -> char* {
        char* p = ws + off;
        off = (off + bytes + 255) & ~(size_t)255;
        return p;
    };
    int* deg_out  = (int*)take((size_t)n * 4);
    int* deg_in   = (int*)take((size_t)n * 4);
    int* cursor   = (int*)take((size_t)n * 4);
    int* row      = (int*)take((size_t)(n + 1) * 4);
    int* partials = (int*)take(4096);
    int2* csr2    = (int2*)take((size_t)e * 8);      // 8 MB
    float* oi     = (float*)take((size_t)n * 4);
    float* ii     = (float*)take((size_t)n * 4);
    float* aggbuf = (float*)take((size_t)total * 4); // 25.6 MB
    float* h1     = (float*)take((size_t)total * 4); // 25.6 MB

    const int tb = 256;
    size_t zbytes = (size_t)((char*)deg_in + (size_t)n * 4 - (char*)deg_out);
    hipMemsetAsync(deg_out, 0, zbytes, stream);

    deg_kernel<<<(e + tb - 1) / tb, tb, 0, stream>>>(src, dst, deg_out, deg_in, e);

    int nchunks = (n + 1023) / 1024;
    scan1_kernel<<<nchunks, 1024, 0, stream>>>(deg_in, row, partials, n);
    scan2_kernel<<<1, 1024, 0, stream>>>(partials, nchunks, row, n);
    scan3_kernel<<<(n + tb - 1) / tb, tb, 0, stream>>>(row, cursor, partials,
                                                       deg_out, deg_in, oi, ii, n);
    scatter_kernel<<<(e + tb - 1) / tb, tb, 0, stream>>>(src, dst, oi, cursor, csr2, e);

    const int ablocks = 2048;
    const int awaves = ablocks * (tb / 64);
    const int gblocks = 512;
    const int gwaves = gblocks * (tb / 64);

    // layer 1
    agg_kernel<<<ablocks, tb, 0, stream>>>((const float4*)x, row, csr2,
                                           (float4*)aggbuf, n, awaves);
    gemm_kernel<false><<<gblocks, tb, 0, stream>>>(aggbuf, ii, W1, b1,
                                                   nullptr, nullptr, h1, n, gwaves);
    // layer 2
    agg_kernel<<<ablocks, tb, 0, stream>>>((const float4*)h1, row, csr2,
                                           (float4*)aggbuf, n, awaves);
    gemm_kernel<true><<<gblocks, tb, 0, stream>>>(aggbuf, ii, W2, b2,
                                                  Wc, bc, (float*)d_out, n, gwaves);
}

// Round 12
// 270.811 us; speedup vs baseline: 1.6331x; 1.2331x over previous
//
#include <hip/hip_runtime.h>

// GCN: 2x GraphConv(norm='both') + leaky_relu + linear classifier.
// Interface (validated R6/R7): x/W/b f32, src/dst int32, out f32.
// R12: rank-trick CSR build (no scatter atomics), oi pre-folded into bf16
// staged features (csr shrinks to 4B/edge, agg gathers halve to 128B/edge),
// agg = quad-per-node float4-lane gather-sum, transform = MFMA bf16 GEMM.
// R11 lesson: preprocessing atomics are sector-traffic bound (~870 GB/s on
// random 32B); remove atomics/bytes, not "add parallelism".

typedef __attribute__((ext_vector_type(8))) short short8;
typedef __attribute__((ext_vector_type(4))) float f32x4;

__device__ __forceinline__ float b2f(unsigned short u) {
    return __uint_as_float(((unsigned int)u) << 16);
}
__device__ __forceinline__ unsigned short f2b(float f) {
    unsigned int i = __float_as_uint(f);
    unsigned int r = (i + 0x7FFFu + ((i >> 16) & 1u)) >> 16;  // RNE
    return (unsigned short)r;
}

// degrees + per-edge rank among same-dst edges (atomic return value)
__global__ void deg_rank_kernel(const int* __restrict__ src, const int* __restrict__ dst,
                                int* dout, int* din, int* rank, int e) {
    int i = blockIdx.x * blockDim.x + threadIdx.x;
    if (i < e) {
        rank[i] = atomicAdd(&din[dst[i]], 1);
        atomicAdd(&dout[src[i]], 1);
    }
}

// ---- exclusive prefix scan of deg_in -> row offsets ----
__global__ void scan1_kernel(const int* __restrict__ deg, int* row, int* partials, int n) {
    __shared__ int s[1024];
    int t = threadIdx.x;
    int i = blockIdx.x * 1024 + t;
    int v = (i < n) ? deg[i] : 0;
    s[t] = v;
    __syncthreads();
    for (int d = 1; d < 1024; d <<= 1) {
        int x = (t >= d) ? s[t - d] : 0;
        __syncthreads();
        s[t] += x;
        __syncthreads();
    }
    if (i < n) row[i] = s[t] - v;  // exclusive within chunk
    if (t == 1023) partials[blockIdx.x] = s[1023];
}

__global__ void scan2_kernel(int* partials, int nchunks, int* row, int n) {
    __shared__ int s[1024];
    int t = threadIdx.x;
    int v = (t < nchunks) ? partials[t] : 0;
    s[t] = v;
    __syncthreads();
    for (int d = 1; d < 1024; d <<= 1) {
        int x = (t >= d) ? s[t - d] : 0;
        __syncthreads();
        s[t] += x;
        __syncthreads();
    }
    if (t < nchunks) partials[t] = s[t] - v;  // exclusive
    if (t == nchunks - 1) row[n] = s[t];      // total == E
}

// add chunk bases; degree rsqrt
__global__ void scan3_kernel(int* row, const int* __restrict__ partials,
                             const int* __restrict__ dout, const int* __restrict__ din,
                             float* oi, float* ii, int n) {
    int i = blockIdx.x * blockDim.x + threadIdx.x;
    if (i < n) {
        row[i] += partials[i >> 10];
        oi[i] = rsqrtf((float)max(dout[i], 1));
        ii[i] = rsqrtf((float)max(din[i], 1));
    }
}

// atomic-free scatter: csr[row[dst]+rank] = src
__global__ void scatter_kernel(const int* __restrict__ src, const int* __restrict__ dst,
                               const int* __restrict__ rank, const int* __restrict__ row,
                               int* __restrict__ csr, int e) {
    int i = blockIdx.x * blockDim.x + threadIdx.x;
    if (i < e) csr[row[dst[i]] + rank[i]] = src[i];
}

// xb = bf16(x * oi[node]), 4 elems/thread
__global__ void xconv_kernel(const float4* __restrict__ x4, const float* __restrict__ oi,
                             ushort4* __restrict__ xb, int quads) {
    int i = blockIdx.x * blockDim.x + threadIdx.x;
    if (i < quads) {
        float s = oi[i >> 4];  // 16 quads per node (64 feats)
        float4 v = x4[i];
        xb[i] = make_ushort4(f2b(v.x * s), f2b(v.y * s), f2b(v.z * s), f2b(v.w * s));
    }
}

// Aggregate: wave = 4 nodes; quad q owns node vbase+q; sublane s = lane&15
// owns feats 4s..4s+3 (ushort4 = 8B). One gather inst serves 4 edges.
// Features are pre-scaled by oi, so this is a plain sum.
__global__ __launch_bounds__(256) void agg_kernel(
    const ushort4* __restrict__ featb, const int* __restrict__ row,
    const int* __restrict__ csr, float4* __restrict__ out4,
    int n, int nwaves) {
    int lane = threadIdx.x & 63;
    int q = lane >> 4, s = lane & 15;
    int wid = blockIdx.x * (blockDim.x >> 6) + (threadIdx.x >> 6);
    int ngroups = (n + 3) >> 2;

    for (int g = wid; g < ngroups; g += nwaves) {
        int v = (g << 2) + q;
        bool valid = v < n;
        int base = 0, cnt = 0;
        if (valid) { base = row[v]; cnt = row[v + 1] - base; }
        float4 a = make_float4(0.f, 0.f, 0.f, 0.f);
        int j = 0;
        for (; j + 3 < cnt; j += 4) {
            int u0 = csr[base + j],     u1 = csr[base + j + 1];
            int u2 = csr[base + j + 2], u3 = csr[base + j + 3];
            ushort4 f0 = featb[(size_t)u0 * 16 + s];
            ushort4 f1 = featb[(size_t)u1 * 16 + s];
            ushort4 f2 = featb[(size_t)u2 * 16 + s];
            ushort4 f3 = featb[(size_t)u3 * 16 + s];
            a.x += b2f(f0.x) + b2f(f1.x) + b2f(f2.x) + b2f(f3.x);
            a.y += b2f(f0.y) + b2f(f1.y) + b2f(f2.y) + b2f(f3.y);
            a.z += b2f(f0.z) + b2f(f1.z) + b2f(f2.z) + b2f(f3.z);
            a.w += b2f(f0.w) + b2f(f1.w) + b2f(f2.w) + b2f(f3.w);
        }
        for (; j < cnt; j++) {
            ushort4 f = featb[(size_t)csr[base + j] * 16 + s];
            a.x += b2f(f.x); a.y += b2f(f.y); a.z += b2f(f.z); a.w += b2f(f.w);
        }
        if (valid) out4[(size_t)v * 16 + s] = a;
    }
}

// Transform: [n x 64] @ W[64 x 64] via mfma_f32_16x16x32_bf16.
// A: m=lane&15, k=quad*8+j; B: n=lane&15, k=quad*8+j; C/D: col=lane&15,
// row=quad*4+reg (all verified R11). ii folded into A; bias+leaky epilogue.
// !FINAL: writes bf16 h1 pre-scaled by oi (feeds agg2 directly).
// FINAL: fuses 64->2 classifier, writes f32 out.
template <bool FINAL>
__global__ __launch_bounds__(256) void gemm_kernel(
    const float* __restrict__ agg, const float* __restrict__ ii,
    const float* __restrict__ oi,
    const float* __restrict__ W, const float* __restrict__ bias,
    const float* __restrict__ Wc, const float* __restrict__ bcl,
    void* __restrict__ out, int n, int nwaves) {
    int lane = threadIdx.x & 63;
    int m15 = lane & 15, quad = lane >> 4;
    int wid = blockIdx.x * (blockDim.x >> 6) + (threadIdx.x >> 6);
    int ngroups = (n + 15) >> 4;

    short8 bf[4][2];
#pragma unroll
    for (int nt = 0; nt < 4; nt++)
#pragma unroll
        for (int kk = 0; kk < 2; kk++)
#pragma unroll
            for (int j = 0; j < 8; j++)
                bf[nt][kk][j] = (short)f2b(W[(kk * 32 + quad * 8 + j) * 64 + nt * 16 + m15]);

    float bias_r[4];
#pragma unroll
    for (int nt = 0; nt < 4; nt++) bias_r[nt] = bias[nt * 16 + m15];

    float wc_r[4][2];
    float bc0 = 0.f, bc1 = 0.f;
    if constexpr (FINAL) {
#pragma unroll
        for (int nt = 0; nt < 4; nt++) {
            wc_r[nt][0] = Wc[(nt * 16 + m15) * 2];
            wc_r[nt][1] = Wc[(nt * 16 + m15) * 2 + 1];
        }
        bc0 = bcl[0];
        bc1 = bcl[1];
    }

    for (int g = wid; g < ngroups; g += nwaves) {
        int rbase = g << 4;
        int rm = min(rbase + m15, n - 1);
        float iiv = ii[rm];

        short8 af[2];
#pragma unroll
        for (int kk = 0; kk < 2; kk++) {
            const float4* p = (const float4*)(agg + (size_t)rm * 64 + kk * 32 + quad * 8);
            float4 x0 = p[0], x1 = p[1];
            af[kk][0] = (short)f2b(x0.x * iiv);
            af[kk][1] = (short)f2b(x0.y * iiv);
            af[kk][2] = (short)f2b(x0.z * iiv);
            af[kk][3] = (short)f2b(x0.w * iiv);
            af[kk][4] = (short)f2b(x1.x * iiv);
            af[kk][5] = (short)f2b(x1.y * iiv);
            af[kk][6] = (short)f2b(x1.z * iiv);
            af[kk][7] = (short)f2b(x1.w * iiv);
        }

        f32x4 acc[4];
#pragma unroll
        for (int nt = 0; nt < 4; nt++) {
            f32x4 z = {0.f, 0.f, 0.f, 0.f};
            z = __builtin_amdgcn_mfma_f32_16x16x32_bf16(af[0], bf[nt][0], z, 0, 0, 0);
            z = __builtin_amdgcn_mfma_f32_16x16x32_bf16(af[1], bf[nt][1], z, 0, 0, 0);
            acc[nt] = z;
        }

        if constexpr (!FINAL) {
#pragma unroll
            for (int r = 0; r < 4; r++) {
                int vr = rbase + quad * 4 + r;
                float os = (vr < n) ? oi[vr] : 0.f;
#pragma unroll
                for (int nt = 0; nt < 4; nt++) {
                    float o = acc[nt][r] + bias_r[nt];
                    o = (o > 0.f) ? o : 0.01f * o;
                    if (vr < n)
                        ((unsigned short*)out)[(size_t)vr * 64 + nt * 16 + m15] = f2b(o * os);
                }
            }
        } else {
#pragma unroll
            for (int r = 0; r < 4; r++) {
                float p0 = 0.f, p1 = 0.f;
#pragma unroll
                for (int nt = 0; nt < 4; nt++) {
                    float o = acc[nt][r] + bias_r[nt];
                    o = (o > 0.f) ? o : 0.01f * o;
                    p0 = fmaf(o, wc_r[nt][0], p0);
                    p1 = fmaf(o, wc_r[nt][1], p1);
                }
#pragma unroll
                for (int off = 1; off < 16; off <<= 1) {
                    p0 += __shfl_xor(p0, off);
                    p1 += __shfl_xor(p1, off);
                }
                int vr = rbase + quad * 4 + r;
                if (m15 == 0 && vr < n)
                    ((float2*)out)[vr] = make_float2(p0 + bc0, p1 + bc1);
            }
        }
    }
}

extern "C" void kernel_launch(void* const* d_in, const int* in_sizes, int n_in,
                              void* d_out, int out_size, void* d_ws, size_t ws_size,
                              hipStream_t stream) {
    const float* x  = (const float*)d_in[0];
    const int* src  = (const int*)d_in[1];
    const int* dst  = (const int*)d_in[2];
    const float* W1 = (const float*)d_in[3];
    const float* b1 = (const float*)d_in[4];
    const float* W2 = (const float*)d_in[5];
    const float* b2 = (const float*)d_in[6];
    const float* Wc = (const float*)d_in[7];
    const float* bc = (const float*)d_in[8];
    int n = in_sizes[0] / 64;
    int e = in_sizes[1];
    int total = n * 64;

    char* ws = (char*)d_ws;
    size_t off = 0;
    auto take = [&](size_t bytes) -> char* {
        char* p = ws + off;
        off = (off + bytes + 255) & ~(size_t)255;
        return p;
    };
    int* deg_out  = (int*)take((size_t)n * 4);
    int* deg_in   = (int*)take((size_t)n * 4);
    int* row      = (int*)take((size_t)(n + 1) * 4);
    int* partials = (int*)take(4096);
    int* rank     = (int*)take((size_t)e * 4);               // 4 MB
    int* csr      = (int*)take((size_t)e * 4);               // 4 MB
    float* oi     = (float*)take((size_t)n * 4);
    float* ii     = (float*)take((size_t)n * 4);
    unsigned short* xb  = (unsigned short*)take((size_t)total * 2);  // 12.8 MB
    unsigned short* h1b = (unsigned short*)take((size_t)total * 2);  // 12.8 MB
    float* aggbuf = (float*)take((size_t)total * 4);         // 25.6 MB

    const int tb = 256;
    size_t zbytes = (size_t)((char*)deg_in + (size_t)n * 4 - (char*)deg_out);
    hipMemsetAsync(deg_out, 0, zbytes, stream);

    deg_rank_kernel<<<(e + tb - 1) / tb, tb, 0, stream>>>(src, dst, deg_out, deg_in,
                                                          rank, e);
    int nchunks = (n + 1023) / 1024;
    scan1_kernel<<<nchunks, 1024, 0, stream>>>(deg_in, row, partials, n);
    scan2_kernel<<<1, 1024, 0, stream>>>(partials, nchunks, row, n);
    scan3_kernel<<<(n + tb - 1) / tb, tb, 0, stream>>>(row, partials,
                                                       deg_out, deg_in, oi, ii, n);
    scatter_kernel<<<(e + tb - 1) / tb, tb, 0, stream>>>(src, dst, rank, row, csr, e);
    xconv_kernel<<<(total / 4 + tb - 1) / tb, tb, 0, stream>>>((const float4*)x, oi,
                                                               (ushort4*)xb, total / 4);

    const int ablocks = 2048;
    const int awaves = ablocks * (tb / 64);
    const int gblocks = 512;
    const int gwaves = gblocks * (tb / 64);

    // layer 1
    agg_kernel<<<ablocks, tb, 0, stream>>>((const ushort4*)xb, row, csr,
                                           (float4*)aggbuf, n, awaves);
    gemm_kernel<false><<<gblocks, tb, 0, stream>>>(aggbuf, ii, oi, W1, b1,
                                                   nullptr, nullptr, h1b, n, gwaves);
    // layer 2
    agg_kernel<<<ablocks, tb, 0, stream>>>((const ushort4*)h1b, row, csr,
                                           (float4*)aggbuf, n, awaves);
    gemm_kernel<true><<<gblocks, tb, 0, stream>>>(aggbuf, ii, nullptr, W2, b2,
                                                  Wc, bc, d_out, n, gwaves);
}

// Round 13
// 264.251 us; speedup vs baseline: 1.6736x; 1.0248x over previous
//
#include <hip/hip_runtime.h>

// GCN: 2x GraphConv(norm='both') + leaky_relu + linear classifier.
// Interface (validated R6/R7): x/W/b f32, src/dst int32, out f32.
// R13: preprocessing rebuilt as bucketed counting sort -- zero global atomics.
// R12 lesson: device-scope atomics cost a 32B memory-side sector each
// (~790 GB/s random ceiling); reduce op count via LDS-local histograms.
// Buckets: 512 nodes wide (<=256 buckets for n<=131072). Layers unchanged:
// bf16 agg (quad-per-node, ushort4 lanes) + MFMA bf16 GEMM.

typedef __attribute__((ext_vector_type(8))) short short8;
typedef __attribute__((ext_vector_type(4))) float f32x4;

#define NPB 256      // partition blocks
#define BSH 9        // bucket shift (width 512)
#define BW  512      // bucket width

__device__ __forceinline__ float b2f(unsigned short u) {
    return __uint_as_float(((unsigned int)u) << 16);
}
__device__ __forceinline__ unsigned short f2b(float f) {
    unsigned int i = __float_as_uint(f);
    unsigned int r = (i + 0x7FFFu + ((i >> 16) & 1u)) >> 16;  // RNE
    return (unsigned short)r;
}

// K1: per-partition-block LDS histograms by dst-bucket and src-bucket.
// cnt layout: [bucket * NPB + pb]
__global__ __launch_bounds__(256) void count_kernel(
    const int* __restrict__ src, const int* __restrict__ dst,
    int* __restrict__ cntD, int* __restrict__ cntS, int e, int chunk) {
    __shared__ int hD[256], hS[256];
    int t = threadIdx.x, pb = blockIdx.x;
    hD[t] = 0; hS[t] = 0;
    __syncthreads();
    int e0 = pb * chunk, e1 = min(e, e0 + chunk);
    for (int i = e0 + t; i < e1; i += 256) {
        atomicAdd(&hD[dst[i] >> BSH], 1);
        atomicAdd(&hS[src[i] >> BSH], 1);
    }
    __syncthreads();
    cntD[t * NPB + pb] = hD[t];
    cntS[t * NPB + pb] = hS[t];
}

// K2: exclusive scan of a 65536-int array in place (single 1024-thread block)
__global__ __launch_bounds__(1024) void scanmat_kernel(int* __restrict__ a) {
    __shared__ int s[1024];
    int t = threadIdx.x;
    int base = t * 64;
    int sum = 0;
    for (int j = 0; j < 64; j++) sum += a[base + j];
    s[t] = sum;
    __syncthreads();
    for (int d = 1; d < 1024; d <<= 1) {
        int x = (t >= d) ? s[t - d] : 0;
        __syncthreads();
        s[t] += x;
        __syncthreads();
    }
    int run = s[t] - sum;  // exclusive prefix of this chunk
    for (int j = 0; j < 64; j++) {
        int v = a[base + j];
        a[base + j] = run;
        run += v;
    }
}

// K3: partition edges into dst-bucketed (src,dst) pairs and src-bucketed src
__global__ __launch_bounds__(256) void part_kernel(
    const int* __restrict__ src, const int* __restrict__ dst,
    const int* __restrict__ cntD, const int* __restrict__ cntS,
    int2* __restrict__ ebuf, int* __restrict__ sbuf, int e, int chunk) {
    __shared__ int cD[256], cS[256];
    int t = threadIdx.x, pb = blockIdx.x;
    cD[t] = cntD[t * NPB + pb];
    cS[t] = cntS[t * NPB + pb];
    __syncthreads();
    int e0 = pb * chunk, e1 = min(e, e0 + chunk);
    for (int i = e0 + t; i < e1; i += 256) {
        int s_ = src[i], d_ = dst[i];
        int pd = atomicAdd(&cD[d_ >> BSH], 1);
        ebuf[pd] = make_int2(s_, d_);
        int ps = atomicAdd(&cS[s_ >> BSH], 1);
        sbuf[ps] = s_;
    }
}

// K4: per-bucket CSR build + in-degree rsqrt. One block per bucket.
__global__ __launch_bounds__(256) void csr_kernel(
    const int2* __restrict__ ebuf, const int* __restrict__ cntD,
    int* __restrict__ row, float* __restrict__ ii, int* __restrict__ csr,
    int n, int e) {
    __shared__ int cnt[BW], cur[BW], ps[256];
    int t = threadIdx.x, b = blockIdx.x;
    int v0 = b << BSH;
    int eb0 = cntD[b * NPB];
    int eb1 = cntD[(b + 1) * NPB];
    cnt[t] = 0; cnt[t + 256] = 0;
    __syncthreads();
    for (int i = eb0 + t; i < eb1; i += 256)
        atomicAdd(&cnt[ebuf[i].y - v0], 1);
    __syncthreads();
    int c0 = cnt[2 * t], c1 = cnt[2 * t + 1];
    int pair = c0 + c1;
    ps[t] = pair;
    __syncthreads();
    for (int d = 1; d < 256; d <<= 1) {
        int x = (t >= d) ? ps[t - d] : 0;
        __syncthreads();
        ps[t] += x;
        __syncthreads();
    }
    int excl = ps[t] - pair;
    cur[2 * t] = excl;
    cur[2 * t + 1] = excl + c0;
    int v = v0 + 2 * t;
    if (v < n) {
        row[v] = eb0 + excl;
        ii[v] = rsqrtf((float)max(c0, 1));
    }
    if (v + 1 < n) {
        row[v + 1] = eb0 + excl + c0;
        ii[v + 1] = rsqrtf((float)max(c1, 1));
    }
    if (b == 0 && t == 0) row[n] = e;
    __syncthreads();
    for (int i = eb0 + t; i < eb1; i += 256) {
        int2 p = ebuf[i];
        int r = atomicAdd(&cur[p.y - v0], 1);
        csr[eb0 + r] = p.x;
    }
}

// K5: per-bucket out-degree rsqrt
__global__ __launch_bounds__(256) void outdeg_kernel(
    const int* __restrict__ sbuf, const int* __restrict__ cntS,
    float* __restrict__ oi, int n) {
    __shared__ int cnt[BW];
    int t = threadIdx.x, b = blockIdx.x;
    int v0 = b << BSH;
    int sb0 = cntS[b * NPB];
    int sb1 = cntS[(b + 1) * NPB];
    cnt[t] = 0; cnt[t + 256] = 0;
    __syncthreads();
    for (int i = sb0 + t; i < sb1; i += 256)
        atomicAdd(&cnt[sbuf[i] - v0], 1);
    __syncthreads();
    for (int j = t; j < BW; j += 256) {
        int v = v0 + j;
        if (v < n) oi[v] = rsqrtf((float)max(cnt[j], 1));
    }
}

// xb = bf16(x * oi[node]), 4 elems/thread
__global__ void xconv_kernel(const float4* __restrict__ x4, const float* __restrict__ oi,
                             ushort4* __restrict__ xb, int quads) {
    int i = blockIdx.x * blockDim.x + threadIdx.x;
    if (i < quads) {
        float s = oi[i >> 4];  // 16 quads per node (64 feats)
        float4 v = x4[i];
        xb[i] = make_ushort4(f2b(v.x * s), f2b(v.y * s), f2b(v.z * s), f2b(v.w * s));
    }
}

// Aggregate: wave = 4 nodes; quad q owns node vbase+q; sublane s = lane&15
// owns feats 4s..4s+3 (ushort4 = 8B). Features pre-scaled by oi.
__global__ __launch_bounds__(256) void agg_kernel(
    const ushort4* __restrict__ featb, const int* __restrict__ row,
    const int* __restrict__ csr, float4* __restrict__ out4,
    int n, int nwaves) {
    int lane = threadIdx.x & 63;
    int q = lane >> 4, s = lane & 15;
    int wid = blockIdx.x * (blockDim.x >> 6) + (threadIdx.x >> 6);
    int ngroups = (n + 3) >> 2;

    for (int g = wid; g < ngroups; g += nwaves) {
        int v = (g << 2) + q;
        bool valid = v < n;
        int base = 0, cnt = 0;
        if (valid) { base = row[v]; cnt = row[v + 1] - base; }
        float4 a = make_float4(0.f, 0.f, 0.f, 0.f);
        int j = 0;
        for (; j + 3 < cnt; j += 4) {
            int u0 = csr[base + j],     u1 = csr[base + j + 1];
            int u2 = csr[base + j + 2], u3 = csr[base + j + 3];
            ushort4 f0 = featb[(size_t)u0 * 16 + s];
            ushort4 f1 = featb[(size_t)u1 * 16 + s];
            ushort4 f2 = featb[(size_t)u2 * 16 + s];
            ushort4 f3 = featb[(size_t)u3 * 16 + s];
            a.x += b2f(f0.x) + b2f(f1.x) + b2f(f2.x) + b2f(f3.x);
            a.y += b2f(f0.y) + b2f(f1.y) + b2f(f2.y) + b2f(f3.y);
            a.z += b2f(f0.z) + b2f(f1.z) + b2f(f2.z) + b2f(f3.z);
            a.w += b2f(f0.w) + b2f(f1.w) + b2f(f2.w) + b2f(f3.w);
        }
        for (; j < cnt; j++) {
            ushort4 f = featb[(size_t)csr[base + j] * 16 + s];
            a.x += b2f(f.x); a.y += b2f(f.y); a.z += b2f(f.z); a.w += b2f(f.w);
        }
        if (valid) out4[(size_t)v * 16 + s] = a;
    }
}

// Transform: [n x 64] @ W[64 x 64] via mfma_f32_16x16x32_bf16 (layout
// verified R11). ii folded into A; bias+leaky epilogue. !FINAL: bf16 h1
// pre-scaled by oi. FINAL: fused 64->2 classifier, f32 out.
template <bool FINAL>
__global__ __launch_bounds__(256) void gemm_kernel(
    const float* __restrict__ agg, const float* __restrict__ ii,
    const float* __restrict__ oi,
    const float* __restrict__ W, const float* __restrict__ bias,
    const float* __restrict__ Wc, const float* __restrict__ bcl,
    void* __restrict__ out, int n, int nwaves) {
    int lane = threadIdx.x & 63;
    int m15 = lane & 15, quad = lane >> 4;
    int wid = blockIdx.x * (blockDim.x >> 6) + (threadIdx.x >> 6);
    int ngroups = (n + 15) >> 4;

    short8 bf[4][2];
#pragma unroll
    for (int nt = 0; nt < 4; nt++)
#pragma unroll
        for (int kk = 0; kk < 2; kk++)
#pragma unroll
            for (int j = 0; j < 8; j++)
                bf[nt][kk][j] = (short)f2b(W[(kk * 32 + quad * 8 + j) * 64 + nt * 16 + m15]);

    float bias_r[4];
#pragma unroll
    for (int nt = 0; nt < 4; nt++) bias_r[nt] = bias[nt * 16 + m15];

    float wc_r[4][2];
    float bc0 = 0.f, bc1 = 0.f;
    if constexpr (FINAL) {
#pragma unroll
        for (int nt = 0; nt < 4; nt++) {
            wc_r[nt][0] = Wc[(nt * 16 + m15) * 2];
            wc_r[nt][1] = Wc[(nt * 16 + m15) * 2 + 1];
        }
        bc0 = bcl[0];
        bc1 = bcl[1];
    }

    for (int g = wid; g < ngroups; g += nwaves) {
        int rbase = g << 4;
        int rm = min(rbase + m15, n - 1);
        float iiv = ii[rm];

        short8 af[2];
#pragma unroll
        for (int kk = 0; kk < 2; kk++) {
            const float4* p = (const float4*)(agg + (size_t)rm * 64 + kk * 32 + quad * 8);
            float4 x0 = p[0], x1 = p[1];
            af[kk][0] = (short)f2b(x0.x * iiv);
            af[kk][1] = (short)f2b(x0.y * iiv);
            af[kk][2] = (short)f2b(x0.z * iiv);
            af[kk][3] = (short)f2b(x0.w * iiv);
            af[kk][4] = (short)f2b(x1.x * iiv);
            af[kk][5] = (short)f2b(x1.y * iiv);
            af[kk][6] = (short)f2b(x1.z * iiv);
            af[kk][7] = (short)f2b(x1.w * iiv);
        }

        f32x4 acc[4];
#pragma unroll
        for (int nt = 0; nt < 4; nt++) {
            f32x4 z = {0.f, 0.f, 0.f, 0.f};
            z = __builtin_amdgcn_mfma_f32_16x16x32_bf16(af[0], bf[nt][0], z, 0, 0, 0);
            z = __builtin_amdgcn_mfma_f32_16x16x32_bf16(af[1], bf[nt][1], z, 0, 0, 0);
            acc[nt] = z;
        }

        if constexpr (!FINAL) {
#pragma unroll
            for (int r = 0; r < 4; r++) {
                int vr = rbase + quad * 4 + r;
                float os = (vr < n) ? oi[vr] : 0.f;
#pragma unroll
                for (int nt = 0; nt < 4; nt++) {
                    float o = acc[nt][r] + bias_r[nt];
                    o = (o > 0.f) ? o : 0.01f * o;
                    if (vr < n)
                        ((unsigned short*)out)[(size_t)vr * 64 + nt * 16 + m15] = f2b(o * os);
                }
            }
        } else {
#pragma unroll
            for (int r = 0; r < 4; r++) {
                float p0 = 0.f, p1 = 0.f;
#pragma unroll
                for (int nt = 0; nt < 4; nt++) {
                    float o = acc[nt][r] + bias_r[nt];
                    o = (o > 0.f) ? o : 0.01f * o;
                    p0 = fmaf(o, wc_r[nt][0], p0);
                    p1 = fmaf(o, wc_r[nt][1], p1);
                }
#pragma unroll
                for (int off = 1; off < 16; off <<= 1) {
                    p0 += __shfl_xor(p0, off);
                    p1 += __shfl_xor(p1, off);
                }
                int vr = rbase + quad * 4 + r;
                if (m15 == 0 && vr < n)
                    ((float2*)out)[vr] = make_float2(p0 + bc0, p1 + bc1);
            }
        }
    }
}

extern "C" void kernel_launch(void* const* d_in, const int* in_sizes, int n_in,
                              void* d_out, int out_size, void* d_ws, size_t ws_size,
                              hipStream_t stream) {
    const float* x  = (const float*)d_in[0];
    const int* src  = (const int*)d_in[1];
    const int* dst  = (const int*)d_in[2];
    const float* W1 = (const float*)d_in[3];
    const float* b1 = (const float*)d_in[4];
    const float* W2 = (const float*)d_in[5];
    const float* b2 = (const float*)d_in[6];
    const float* Wc = (const float*)d_in[7];
    const float* bc = (const float*)d_in[8];
    int n = in_sizes[0] / 64;
    int e = in_sizes[1];
    int total = n * 64;
    int nbuck = (n + BW - 1) >> BSH;           // <=256 for n<=131072

    char* ws = (char*)d_ws;
    size_t off = 0;
    auto take = [&](size_t bytes) -> char* {
        char* p = ws + off;
        off = (off + bytes + 255) & ~(size_t)255;
        return p;
    };
    int* cntD     = (int*)take(256 * NPB * 4);               // 256 KB
    int* cntS     = (int*)take(256 * NPB * 4);               // 256 KB
    int2* ebuf    = (int2*)take((size_t)e * 8);              // 8 MB
    int* sbuf     = (int*)take((size_t)e * 4);               // 4 MB
    int* row      = (int*)take((size_t)(n + 1) * 4);
    int* csr      = (int*)take((size_t)e * 4);               // 4 MB
    float* oi     = (float*)take((size_t)n * 4);
    float* ii     = (float*)take((size_t)n * 4);
    unsigned short* xb  = (unsigned short*)take((size_t)total * 2);  // 12.8 MB
    unsigned short* h1b = (unsigned short*)take((size_t)total * 2);  // 12.8 MB
    float* aggbuf = (float*)take((size_t)total * 4);         // 25.6 MB

    const int tb = 256;
    int chunk = (e + NPB - 1) / NPB;

    count_kernel<<<NPB, tb, 0, stream>>>(src, dst, cntD, cntS, e, chunk);
    scanmat_kernel<<<1, 1024, 0, stream>>>(cntD);
    scanmat_kernel<<<1, 1024, 0, stream>>>(cntS);
    part_kernel<<<NPB, tb, 0, stream>>>(src, dst, cntD, cntS, ebuf, sbuf, e, chunk);
    csr_kernel<<<nbuck, tb, 0, stream>>>(ebuf, cntD, row, ii, csr, n, e);
    outdeg_kernel<<<nbuck, tb, 0, stream>>>(sbuf, cntS, oi, n);
    xconv_kernel<<<(total / 4 + tb - 1) / tb, tb, 0, stream>>>((const float4*)x, oi,
                                                               (ushort4*)xb, total / 4);

    const int ablocks = 2048;
    const int awaves = ablocks * (tb / 64);
    const int gblocks = 512;
    const int gwaves = gblocks * (tb / 64);

    // layer 1
    agg_kernel<<<ablocks, tb, 0, stream>>>((const ushort4*)xb, row, csr,
                                           (float4*)aggbuf, n, awaves);
    gemm_kernel<false><<<gblocks, tb, 0, stream>>>(aggbuf, ii, oi, W1, b1,
                                                   nullptr, nullptr, h1b, n, gwaves);
    // layer 2
    agg_kernel<<<ablocks, tb, 0, stream>>>((const ushort4*)h1b, row, csr,
                                           (float4*)aggbuf, n, awaves);
    gemm_kernel<true><<<gblocks, tb, 0, stream>>>(aggbuf, ii, nullptr, W2, b2,
                                                  Wc, bc, d_out, n, gwaves);
}

// Round 14
// 234.693 us; speedup vs baseline: 1.8844x; 1.1259x over previous
//
#include <hip/hip_runtime.h>

// GCN: 2x GraphConv(norm='both') + leaky_relu + linear classifier.
// Interface (validated R6/R7): x/W/b f32, src/dst int32, out f32.
// R14: packed bucket sort (ebuf u32 = src<<9|dstLocal, sbuf u16 local),
// fused per-bucket kernel (csr build + out-deg + x->bf16 conversion),
// merged scans, agg unroll-8. Layers: bf16 quad-gather agg + MFMA GEMM.
// Note: ~42us/iter fillBuffer(d_ws poison) is harness overhead, not ours.

typedef __attribute__((ext_vector_type(8))) short short8;
typedef __attribute__((ext_vector_type(4))) float f32x4;

#define NPB 256      // partition blocks
#define BSH 9        // bucket shift (width 512)
#define BW  512      // bucket width; n <= 131072 -> <=256 buckets

__device__ __forceinline__ float b2f(unsigned short u) {
    return __uint_as_float(((unsigned int)u) << 16);
}
__device__ __forceinline__ unsigned short f2b(float f) {
    unsigned int i = __float_as_uint(f);
    unsigned int r = (i + 0x7FFFu + ((i >> 16) & 1u)) >> 16;  // RNE
    return (unsigned short)r;
}

// K1: per-partition-block LDS histograms by dst-bucket and src-bucket.
__global__ __launch_bounds__(256) void count_kernel(
    const int* __restrict__ src, const int* __restrict__ dst,
    int* __restrict__ cntD, int* __restrict__ cntS, int e, int chunk) {
    __shared__ int hD[256], hS[256];
    int t = threadIdx.x, pb = blockIdx.x;
    hD[t] = 0; hS[t] = 0;
    __syncthreads();
    int e0 = pb * chunk, e1 = min(e, e0 + chunk);
    for (int i = e0 + t; i < e1; i += 256) {
        atomicAdd(&hD[dst[i] >> BSH], 1);
        atomicAdd(&hS[src[i] >> BSH], 1);
    }
    __syncthreads();
    cntD[t * NPB + pb] = hD[t];
    cntS[t * NPB + pb] = hS[t];
}

// K2: exclusive scan of two 65536-int arrays (block 0: cntD, block 1: cntS)
__global__ __launch_bounds__(1024) void scanmat_kernel(int* __restrict__ cntD,
                                                       int* __restrict__ cntS) {
    int* a = (blockIdx.x == 0) ? cntD : cntS;
    __shared__ int s[1024];
    int t = threadIdx.x;
    int base = t * 64;
    int sum = 0;
    for (int j = 0; j < 64; j++) sum += a[base + j];
    s[t] = sum;
    __syncthreads();
    for (int d = 1; d < 1024; d <<= 1) {
        int x = (t >= d) ? s[t - d] : 0;
        __syncthreads();
        s[t] += x;
        __syncthreads();
    }
    int run = s[t] - sum;
    for (int j = 0; j < 64; j++) {
        int v = a[base + j];
        a[base + j] = run;
        run += v;
    }
}

// K3: partition. ebuf u32 = src<<9 | dstLocal; sbuf u16 = srcLocal.
__global__ __launch_bounds__(256) void part_kernel(
    const int* __restrict__ src, const int* __restrict__ dst,
    const int* __restrict__ cntD, const int* __restrict__ cntS,
    unsigned int* __restrict__ ebuf, unsigned short* __restrict__ sbuf,
    int e, int chunk) {
    __shared__ int cD[256], cS[256];
    int t = threadIdx.x, pb = blockIdx.x;
    cD[t] = cntD[t * NPB + pb];
    cS[t] = cntS[t * NPB + pb];
    __syncthreads();
    int e0 = pb * chunk, e1 = min(e, e0 + chunk);
    for (int i = e0 + t; i < e1; i += 256) {
        int s_ = src[i], d_ = dst[i];
        int pd = atomicAdd(&cD[d_ >> BSH], 1);
        ebuf[pd] = ((unsigned int)s_ << BSH) | (unsigned int)(d_ & (BW - 1));
        int ps_ = atomicAdd(&cS[s_ >> BSH], 1);
        sbuf[ps_] = (unsigned short)(s_ & (BW - 1));
    }
}

// K4: per-bucket fused: in-deg hist -> row/ii/cursors -> csr scatter;
// out-deg hist -> oi; x -> bf16*oi conversion for the bucket's nodes.
__global__ __launch_bounds__(256) void bucket_kernel(
    const unsigned int* __restrict__ ebuf, const unsigned short* __restrict__ sbuf,
    const int* __restrict__ cntD, const int* __restrict__ cntS,
    const float4* __restrict__ x4,
    int* __restrict__ row, float* __restrict__ ii, float* __restrict__ oi,
    int* __restrict__ csr, ushort4* __restrict__ xb, int n, int e) {
    __shared__ int cnt[BW], cur[BW], ocnt[BW], ps[256];
    __shared__ float ol[BW];
    int t = threadIdx.x, b = blockIdx.x;
    int v0 = b << BSH;
    int eb0 = cntD[b * NPB], eb1 = cntD[(b + 1) * NPB];
    int sb0 = cntS[b * NPB], sb1 = cntS[(b + 1) * NPB];
    cnt[t] = 0; cnt[t + 256] = 0;
    ocnt[t] = 0; ocnt[t + 256] = 0;
    __syncthreads();
    for (int i = eb0 + t; i < eb1; i += 256)
        atomicAdd(&cnt[ebuf[i] & (BW - 1)], 1);
    for (int i = sb0 + t; i < sb1; i += 256)
        atomicAdd(&ocnt[sbuf[i]], 1);
    __syncthreads();
    // scan in-degrees (2 per thread)
    int c0 = cnt[2 * t], c1 = cnt[2 * t + 1];
    int pair = c0 + c1;
    ps[t] = pair;
    __syncthreads();
    for (int d = 1; d < 256; d <<= 1) {
        int x = (t >= d) ? ps[t - d] : 0;
        __syncthreads();
        ps[t] += x;
        __syncthreads();
    }
    int excl = ps[t] - pair;
    cur[2 * t] = excl;
    cur[2 * t + 1] = excl + c0;
    int v = v0 + 2 * t;
    if (v < n) {
        row[v] = eb0 + excl;
        ii[v] = rsqrtf((float)max(c0, 1));
    }
    if (v + 1 < n) {
        row[v + 1] = eb0 + excl + c0;
        ii[v + 1] = rsqrtf((float)max(c1, 1));
    }
    if (b == 0 && t == 0) row[n] = e;
    // out-degree rsqrt -> LDS + global
    for (int j = t; j < BW; j += 256) {
        float o = rsqrtf((float)max(ocnt[j], 1));
        ol[j] = o;
        int vv = v0 + j;
        if (vv < n) oi[vv] = o;
    }
    __syncthreads();
    // csr scatter (L2-local: bucket run is ~few tens of KB)
    for (int i = eb0 + t; i < eb1; i += 256) {
        unsigned int p = ebuf[i];
        int r = atomicAdd(&cur[p & (BW - 1)], 1);
        csr[eb0 + r] = (int)(p >> BSH);
    }
    // x -> bf16 * oi for this bucket's nodes (coalesced)
    int nloc = min(BW, n - v0);
    for (int i = t; i < nloc * 16; i += 256) {
        int vl = i >> 4, q = i & 15;
        float s = ol[vl];
        float4 val = x4[(size_t)(v0 + vl) * 16 + q];
        xb[(size_t)(v0 + vl) * 16 + q] =
            make_ushort4(f2b(val.x * s), f2b(val.y * s), f2b(val.z * s), f2b(val.w * s));
    }
}

// Aggregate: wave = 4 nodes; quad q owns node vbase+q; sublane s = lane&15
// owns feats 4s..4s+3 (ushort4 = 8B). Features pre-scaled by oi. Unroll 8.
__global__ __launch_bounds__(256) void agg_kernel(
    const ushort4* __restrict__ featb, const int* __restrict__ row,
    const int* __restrict__ csr, float4* __restrict__ out4,
    int n, int nwaves) {
    int lane = threadIdx.x & 63;
    int q = lane >> 4, s = lane & 15;
    int wid = blockIdx.x * (blockDim.x >> 6) + (threadIdx.x >> 6);
    int ngroups = (n + 3) >> 2;

    for (int g = wid; g < ngroups; g += nwaves) {
        int v = (g << 2) + q;
        bool valid = v < n;
        int base = 0, cnt = 0;
        if (valid) { base = row[v]; cnt = row[v + 1] - base; }
        float4 a = make_float4(0.f, 0.f, 0.f, 0.f);
        int j = 0;
        for (; j + 7 < cnt; j += 8) {
            int u[8];
#pragma unroll
            for (int k = 0; k < 8; k++) u[k] = csr[base + j + k];
#pragma unroll
            for (int k = 0; k < 8; k++) {
                ushort4 f = featb[(size_t)u[k] * 16 + s];
                a.x += b2f(f.x); a.y += b2f(f.y); a.z += b2f(f.z); a.w += b2f(f.w);
            }
        }
        for (; j + 3 < cnt; j += 4) {
            int u[4];
#pragma unroll
            for (int k = 0; k < 4; k++) u[k] = csr[base + j + k];
#pragma unroll
            for (int k = 0; k < 4; k++) {
                ushort4 f = featb[(size_t)u[k] * 16 + s];
                a.x += b2f(f.x); a.y += b2f(f.y); a.z += b2f(f.z); a.w += b2f(f.w);
            }
        }
        for (; j < cnt; j++) {
            ushort4 f = featb[(size_t)csr[base + j] * 16 + s];
            a.x += b2f(f.x); a.y += b2f(f.y); a.z += b2f(f.z); a.w += b2f(f.w);
        }
        if (valid) out4[(size_t)v * 16 + s] = a;
    }
}

// Transform: [n x 64] @ W[64 x 64] via mfma_f32_16x16x32_bf16 (layout
// verified R11). ii folded into A; bias+leaky epilogue. !FINAL: bf16 h1
// pre-scaled by oi. FINAL: fused 64->2 classifier, f32 out.
template <bool FINAL>
__global__ __launch_bounds__(256) void gemm_kernel(
    const float* __restrict__ agg, const float* __restrict__ ii,
    const float* __restrict__ oi,
    const float* __restrict__ W, const float* __restrict__ bias,
    const float* __restrict__ Wc, const float* __restrict__ bcl,
    void* __restrict__ out, int n, int nwaves) {
    int lane = threadIdx.x & 63;
    int m15 = lane & 15, quad = lane >> 4;
    int wid = blockIdx.x * (blockDim.x >> 6) + (threadIdx.x >> 6);
    int ngroups = (n + 15) >> 4;

    short8 bf[4][2];
#pragma unroll
    for (int nt = 0; nt < 4; nt++)
#pragma unroll
        for (int kk = 0; kk < 2; kk++)
#pragma unroll
            for (int j = 0; j < 8; j++)
                bf[nt][kk][j] = (short)f2b(W[(kk * 32 + quad * 8 + j) * 64 + nt * 16 + m15]);

    float bias_r[4];
#pragma unroll
    for (int nt = 0; nt < 4; nt++) bias_r[nt] = bias[nt * 16 + m15];

    float wc_r[4][2];
    float bc0 = 0.f, bc1 = 0.f;
    if constexpr (FINAL) {
#pragma unroll
        for (int nt = 0; nt < 4; nt++) {
            wc_r[nt][0] = Wc[(nt * 16 + m15) * 2];
            wc_r[nt][1] = Wc[(nt * 16 + m15) * 2 + 1];
        }
        bc0 = bcl[0];
        bc1 = bcl[1];
    }

    for (int g = wid; g < ngroups; g += nwaves) {
        int rbase = g << 4;
        int rm = min(rbase + m15, n - 1);
        float iiv = ii[rm];

        short8 af[2];
#pragma unroll
        for (int kk = 0; kk < 2; kk++) {
            const float4* p = (const float4*)(agg + (size_t)rm * 64 + kk * 32 + quad * 8);
            float4 x0 = p[0], x1 = p[1];
            af[kk][0] = (short)f2b(x0.x * iiv);
            af[kk][1] = (short)f2b(x0.y * iiv);
            af[kk][2] = (short)f2b(x0.z * iiv);
            af[kk][3] = (short)f2b(x0.w * iiv);
            af[kk][4] = (short)f2b(x1.x * iiv);
            af[kk][5] = (short)f2b(x1.y * iiv);
            af[kk][6] = (short)f2b(x1.z * iiv);
            af[kk][7] = (short)f2b(x1.w * iiv);
        }

        f32x4 acc[4];
#pragma unroll
        for (int nt = 0; nt < 4; nt++) {
            f32x4 z = {0.f, 0.f, 0.f, 0.f};
            z = __builtin_amdgcn_mfma_f32_16x16x32_bf16(af[0], bf[nt][0], z, 0, 0, 0);
            z = __builtin_amdgcn_mfma_f32_16x16x32_bf16(af[1], bf[nt][1], z, 0, 0, 0);
            acc[nt] = z;
        }

        if constexpr (!FINAL) {
#pragma unroll
            for (int r = 0; r < 4; r++) {
                int vr = rbase + quad * 4 + r;
                float os = (vr < n) ? oi[vr] : 0.f;
#pragma unroll
                for (int nt = 0; nt < 4; nt++) {
                    float o = acc[nt][r] + bias_r[nt];
                    o = (o > 0.f) ? o : 0.01f * o;
                    if (vr < n)
                        ((unsigned short*)out)[(size_t)vr * 64 + nt * 16 + m15] = f2b(o * os);
                }
            }
        } else {
#pragma unroll
            for (int r = 0; r < 4; r++) {
                float p0 = 0.f, p1 = 0.f;
#pragma unroll
                for (int nt = 0; nt < 4; nt++) {
                    float o = acc[nt][r] + bias_r[nt];
                    o = (o > 0.f) ? o : 0.01f * o;
                    p0 = fmaf(o, wc_r[nt][0], p0);
                    p1 = fmaf(o, wc_r[nt][1], p1);
                }
#pragma unroll
                for (int off = 1; off < 16; off <<= 1) {
                    p0 += __shfl_xor(p0, off);
                    p1 += __shfl_xor(p1, off);
                }
                int vr = rbase + quad * 4 + r;
                if (m15 == 0 && vr < n)
                    ((float2*)out)[vr] = make_float2(p0 + bc0, p1 + bc1);
            }
        }
    }
}

extern "C" void kernel_launch(void* const* d_in, const int* in_sizes, int n_in,
                              void* d_out, int out_size, void* d_ws, size_t ws_size,
                              hipStream_t stream) {
    const float* x  = (const float*)d_in[0];
    const int* src  = (const int*)d_in[1];
    const int* dst  = (const int*)d_in[2];
    const float* W1 = (const float*)d_in[3];
    const float* b1 = (const float*)d_in[4];
    const float* W2 = (const float*)d_in[5];
    const float* b2 = (const float*)d_in[6];
    const float* Wc = (const float*)d_in[7];
    const float* bc = (const float*)d_in[8];
    int n = in_sizes[0] / 64;
    int e = in_sizes[1];
    int total = n * 64;
    int nbuck = (n + BW - 1) >> BSH;

    char* ws = (char*)d_ws;
    size_t off = 0;
    auto take = [&](size_t bytes) -> char* {
        char* p = ws + off;
        off = (off + bytes + 255) & ~(size_t)255;
        return p;
    };
    int* cntD = (int*)take(256 * NPB * 4);
    int* cntS = (int*)take(256 * NPB * 4);
    unsigned int* ebuf = (unsigned int*)take((size_t)e * 4);     // 4 MB
    unsigned short* sbuf = (unsigned short*)take((size_t)e * 2); // 2 MB
    int* row  = (int*)take((size_t)(n + 1) * 4);
    int* csr  = (int*)take((size_t)e * 4);                       // 4 MB
    float* oi = (float*)take((size_t)n * 4);
    float* ii = (float*)take((size_t)n * 4);
    unsigned short* xb  = (unsigned short*)take((size_t)total * 2);  // 12.8 MB
    unsigned short* h1b = (unsigned short*)take((size_t)total * 2);  // 12.8 MB
    float* aggbuf = (float*)take((size_t)total * 4);             // 25.6 MB

    const int tb = 256;
    int chunk = (e + NPB - 1) / NPB;

    count_kernel<<<NPB, tb, 0, stream>>>(src, dst, cntD, cntS, e, chunk);
    scanmat_kernel<<<2, 1024, 0, stream>>>(cntD, cntS);
    part_kernel<<<NPB, tb, 0, stream>>>(src, dst, cntD, cntS, ebuf, sbuf, e, chunk);
    bucket_kernel<<<nbuck, tb, 0, stream>>>(ebuf, sbuf, cntD, cntS, (const float4*)x,
                                            row, ii, oi, csr, (ushort4*)xb, n, e);

    const int ablocks = 2048;
    const int awaves = ablocks * (tb / 64);
    const int gblocks = 512;
    const int gwaves = gblocks * (tb / 64);

    // layer 1
    agg_kernel<<<ablocks, tb, 0, stream>>>((const ushort4*)xb, row, csr,
                                           (float4*)aggbuf, n, awaves);
    gemm_kernel<false><<<gblocks, tb, 0, stream>>>(aggbuf, ii, oi, W1, b1,
                                                   nullptr, nullptr, h1b, n, gwaves);
    // layer 2
    agg_kernel<<<ablocks, tb, 0, stream>>>((const ushort4*)h1b, row, csr,
                                           (float4*)aggbuf, n, awaves);
    gemm_kernel<true><<<gblocks, tb, 0, stream>>>(aggbuf, ii, nullptr, W2, b2,
                                                  Wc, bc, d_out, n, gwaves);
}